// Round 12
// baseline (158.310 us; speedup 1.0000x reference)
//
#include <hip/hip_runtime.h>

typedef unsigned short ushort_t;
typedef ushort_t u16x8 __attribute__((ext_vector_type(8)));
typedef __bf16 bf16x8 __attribute__((ext_vector_type(8)));
typedef float f32x4 __attribute__((ext_vector_type(4)));

#define DET 736
#define HALF 368           // real half-size (even or odd samples)
#define NTT 12             // K-tiles of 32 (padded K = 384)
#define CPB2 (NTT * 64)    // 768 frag-chunks per 16-col block of B'
#define NRB 1152           // M/16 row-blocks (M = 18432)
#define NCB 23             // real half-col blocks (368/16)

__device__ __forceinline__ ushort_t f2bf(float f) {
    return __builtin_bit_cast(ushort_t, (__bf16)f);
}

// ---------------------------------------------------------------------------
// PARITY SPLIT (verified R7/R8/R11):
//   OUT[m][2i]   = sum_j x[m][2j+1] Be[i][j]  +  h0 g(2i)   x[m][2i]
//   OUT[m][2i+1] = sum_j x[m][2j]   Bo[i][j]  +  h0 g(2i+1) x[m][2i+1]
// ROUND 12: single fused GEMM, A read EXACTLY ONCE.  R11's decomposition:
// gemm ~40 us because ~280 MB crossed L3/L2 (A' x3 strip re-read x2 in-block
// duplication + sino diag).  Now each wave owns 1 row-block (16 rows) and
// sweeps ALL 23 half-col blocks: its 16 fp32 sino rows are loaded once into a
// REGISTER panel (in-register parity split, bit-identical to old prep_af),
// so prep_af + A' arrays + all A re-reads are gone.  B' (0.59 MB) is
// L1/L2-resident.  Dense float2 stores (R11 parity-pair trick).  No LDS,
// no barriers.  HBM floor: sino 54 R + C 54 W + B 0.6 ~ 17 us.
// ---------------------------------------------------------------------------

// Be[i][j] = g(2j+1) h[2(j-i)+1]  (even outputs);  Bo[i][j] = g(2j) h[2(j-i)-1].
// Frag-major: chunk (cb,t,lane): i = cb*16+(lane&15), j = t*32+(lane>>4)*8+e.
// (verified R7/R8/R11, unchanged)
__global__ void prep_bf(const float* __restrict__ filt,
                        ushort_t* __restrict__ Be, ushort_t* __restrict__ Bo) {
    int c = blockIdx.x * blockDim.x + threadIdx.x;   // exact: 24*CPB2 = 18432
    int cb  = c / CPB2;
    int rem = c - cb * CPB2;
    int t = rem >> 6, lane = rem & 63;
    int i = cb * 16 + (lane & 15);
    int quad = lane >> 4;
    u16x8 ve, vo;
#pragma unroll
    for (int e = 0; e < 8; ++e) {
        int j = t * 32 + quad * 8 + e;
        bool real = (j < HALF) && (i < HALF);
        int de = 2 * (j - i) + 1 + 735;                       // clamped indices
        int do_ = de - 2;
        de  = de  < 0 ? 0 : (de  > 1470 ? 1470 : de);
        do_ = do_ < 0 ? 0 : (do_ > 1470 ? 1470 : do_);
        float ge = 0.05f * cosf(((float)(2 * j + 1) - 367.5f) * 0.001f);
        float go = 0.05f * cosf(((float)(2 * j)     - 367.5f) * 0.001f);
        float fe = filt[de] * ge;
        float fo = filt[do_] * go;
        ve[e] = real ? f2bf(fe) : (ushort_t)0;
        vo[e] = real ? f2bf(fo) : (ushort_t)0;
    }
    *(u16x8*)(Be + (size_t)c * 8) = ve;
    *(u16x8*)(Bo + (size_t)c * 8) = vo;
}

// Block = 256 thr = 4 waves; wave = 1 row-block (16 rows) x all 368 half-cols
// x both parities.  Grid = 288 blocks (~3 blocks/CU at ~160 VGPR).
__global__ __launch_bounds__(256) void gemm_direct(
    const float* __restrict__ sino,
    const ushort_t* __restrict__ Be, const ushort_t* __restrict__ Bo,
    const float* __restrict__ filt,
    float* __restrict__ C)
{
    const int tid  = threadIdx.x;
    const int lane = tid & 63;
    const int wid  = tid >> 6;     // 0..3
    const int quad = lane >> 4;
    const int l16  = lane & 15;

    const int rblk = blockIdx.x * 4 + wid;           // 0..1151

    // ---- A register panel: lane's row, all K, parity-split in-register ----
    // ae[t] = odd samples (feed even outputs), ao[t] = even samples.
    const float* arow = sino + ((size_t)rblk * 16 + l16) * DET;
    u16x8 ae[NTT], ao[NTT];
#pragma unroll
    for (int t = 0; t < NTT; ++t) {
        const int j0 = t * 32 + quad * 8;
        if (j0 < HALF) {           // j0 <= 360 -> 16 floats [2j0, 2j0+16) in-bounds
            const float* g = arow + 2 * j0;
            f32x4 w0 = *(const f32x4*)(g);
            f32x4 w1 = *(const f32x4*)(g + 4);
            f32x4 w2 = *(const f32x4*)(g + 8);
            f32x4 w3 = *(const f32x4*)(g + 12);
            u16x8 ve, vo;
            ve[0] = f2bf(w0[1]); vo[0] = f2bf(w0[0]);
            ve[1] = f2bf(w0[3]); vo[1] = f2bf(w0[2]);
            ve[2] = f2bf(w1[1]); vo[2] = f2bf(w1[0]);
            ve[3] = f2bf(w1[3]); vo[3] = f2bf(w1[2]);
            ve[4] = f2bf(w2[1]); vo[4] = f2bf(w2[0]);
            ve[5] = f2bf(w2[3]); vo[5] = f2bf(w2[2]);
            ve[6] = f2bf(w3[1]); vo[6] = f2bf(w3[0]);
            ve[7] = f2bf(w3[3]); vo[7] = f2bf(w3[2]);
            ae[t] = ve; ao[t] = vo;
        } else {
            ae[t] = (u16x8){0,0,0,0,0,0,0,0};
            ao[t] = (u16x8){0,0,0,0,0,0,0,0};
        }
    }

    const float h0 = filt[735];
    const size_t lane_off = (size_t)lane * 8;

    // ---- sweep all half-col blocks; acc lives in 8 regs per parity-pair ----
#pragma unroll 1
    for (int cb = 0; cb < NCB; ++cb) {
        const ushort_t* be_p = Be + (size_t)cb * (CPB2 * 8) + lane_off;
        const ushort_t* bo_p = Bo + (size_t)cb * (CPB2 * 8) + lane_off;

        f32x4 acc_e = (f32x4){0.f, 0.f, 0.f, 0.f};
        f32x4 acc_o = (f32x4){0.f, 0.f, 0.f, 0.f};

        u16x8 be_c = *(const u16x8*)(be_p);
        u16x8 bo_c = *(const u16x8*)(bo_p);
#pragma unroll
        for (int t = 0; t < NTT; ++t) {
            u16x8 be_n, bo_n;
            if (t + 1 < NTT) {
                be_n = *(const u16x8*)(be_p + (t + 1) * 512);
                bo_n = *(const u16x8*)(bo_p + (t + 1) * 512);
            }
            acc_e = __builtin_amdgcn_mfma_f32_16x16x32_bf16(
                __builtin_bit_cast(bf16x8, ae[t]),
                __builtin_bit_cast(bf16x8, be_c), acc_e, 0, 0, 0);
            acc_o = __builtin_amdgcn_mfma_f32_16x16x32_bf16(
                __builtin_bit_cast(bf16x8, ao[t]),
                __builtin_bit_cast(bf16x8, bo_c), acc_o, 0, 0, 0);
            if (t + 1 < NTT) { be_c = be_n; bo_c = bo_n; }
        }

        // epilogue: lane l16 holds cols (2*ic, 2*ic+1) -> dense float2 stores
        const int ic = cb * 16 + l16;                // <= 367, always real
        const float gw_e = h0 * 0.05f * cosf(((float)(2 * ic)     - 367.5f) * 0.001f);
        const float gw_o = h0 * 0.05f * cosf(((float)(2 * ic + 1) - 367.5f) * 0.001f);
#pragma unroll
        for (int r = 0; r < 4; ++r) {
            const size_t rowg = (size_t)rblk * 16 + quad * 4 + r;
            const float2 xd = *(const float2*)(sino + rowg * DET + 2 * ic);
            float2 o;
            o.x = acc_e[r] + gw_e * xd.x;
            o.y = acc_o[r] + gw_o * xd.y;
            *(float2*)(C + rowg * DET + 2 * ic) = o;
        }
    }
}

extern "C" void kernel_launch(void* const* d_in, const int* in_sizes, int n_in,
                              void* d_out, int out_size, void* d_ws, size_t ws_size,
                              hipStream_t stream) {
    const float* sino = (const float*)d_in[0];
    const float* filt = (const float*)d_in[1];
    (void)in_sizes; (void)n_in; (void)out_size; (void)ws_size;

    const size_t BSZ = (size_t)24 * CPB2 * 8;    // 147,456 elems per B' array

    ushort_t* Be = (ushort_t*)d_ws;              // 590 KB total workspace
    ushort_t* Bo = Be + BSZ;
    float* out = (float*)d_out;

    prep_bf<<<72, 256, 0, stream>>>(filt, Be, Bo);

    gemm_direct<<<NRB / 4, 256, 0, stream>>>(sino, Be, Bo, filt, out);
}